// Round 5
// baseline (310.367 us; speedup 1.0000x reference)
//
#include <hip/hip_runtime.h>
#include <stdint.h>
#include <stddef.h>

#define D_DIM 1024
#define T_LEN 4096
#define B_SZ 8
#define M_ROWS 32768   // B_SZ * T_LEN
#define KTOT 1024
#define CHUNK 64
#define NCHUNK 64      // T_LEN / CHUNK

typedef unsigned short u16;
typedef unsigned short u16x8 __attribute__((ext_vector_type(8)));
typedef __bf16 bf16x8 __attribute__((ext_vector_type(8)));
typedef float f32x4 __attribute__((ext_vector_type(4)));

__device__ __forceinline__ u16 f2bf(float f) {
    union { float f; unsigned u; } v; v.f = f;
    unsigned r = v.u + 0x7fffu + ((v.u >> 16) & 1u);
    return (u16)(r >> 16);
}
__device__ __forceinline__ float bf2f(u16 h) {
    union { unsigned u; float f; } v; v.u = ((unsigned)h) << 16;
    return v.f;
}

// ---------------- f32 -> bf16 conversion (vectorized) ----------------
__global__ void convert_kernel(const float* __restrict__ src, u16* __restrict__ dst, int n4) {
    int i = blockIdx.x * blockDim.x + threadIdx.x;
    int stride = gridDim.x * blockDim.x;
    for (int j = i; j < n4; j += stride) {
        float4 v = ((const float4*)src)[j];
        ushort4 o;
        o.x = f2bf(v.x); o.y = f2bf(v.y); o.z = f2bf(v.z); o.w = f2bf(v.w);
        ((ushort4*)dst)[j] = o;
    }
}

// three weight matrices in one launch
__global__ void convert3_kernel(const float* __restrict__ s0, const float* __restrict__ s1,
                                const float* __restrict__ s2,
                                u16* __restrict__ d0, u16* __restrict__ d1, u16* __restrict__ d2,
                                int n4each) {
    int i = blockIdx.x * blockDim.x + threadIdx.x;
    int total = 3 * n4each;
    int stride = gridDim.x * blockDim.x;
    for (int j = i; j < total; j += stride) {
        int which = j / n4each;
        int off = j - which * n4each;
        const float* s = which == 0 ? s0 : (which == 1 ? s1 : s2);
        u16* d = which == 0 ? d0 : (which == 1 ? d1 : d2);
        float4 v = ((const float4*)s)[off];
        ushort4 o;
        o.x = f2bf(v.x); o.y = f2bf(v.y); o.z = f2bf(v.z); o.w = f2bf(v.w);
        ((ushort4*)d)[off] = o;
    }
}

// ---------------- async global->LDS, 16B per lane ----------------
__device__ __forceinline__ void gload16(const u16* g, u16* l) {
    __builtin_amdgcn_global_load_lds(
        (const __attribute__((address_space(1))) void*)g,
        (__attribute__((address_space(3))) void*)l,
        16, 0, 0);
}

// ---------------- m201-style pipelined GEMM: C[row,col] = sum_k A[row,k]*W[col,k]
// BK=32, 4 LDS buffers, reads issued BEFORE barrier / counted lgkm AFTER barrier,
// register ping-pong fragments, vmcnt(4) once per K-step, XCD-swizzled grid.
// DUAL:  BM=256,BN=128, wave 64x64 per B; u=sigmoid(accK+bk)*(accV+bv) -> bf16
// single:BM=256,BN=256, wave 128x64;    out=(acc+bq)/mass -> f32
template<bool DUAL>
__global__ __launch_bounds__(512, 2) void gemm4_kernel(
    const u16* __restrict__ A,
    const u16* __restrict__ B0g,
    const u16* __restrict__ B1g,
    const float* __restrict__ bias0,
    const float* __restrict__ bias1,
    u16* __restrict__ Uout,
    float* __restrict__ Fout)
{
    constexpr int BM = 256;
    constexpr int BN = DUAL ? 128 : 256;
    constexpr int MFR = DUAL ? 4 : 8;
    constexpr int BUF = 16384;             // u16 per buffer (32KB)
    constexpr int NT = KTOT / 32;          // 32 K-steps

    __shared__ u16 smem[4 * BUF];          // 128 KB

    const int tid  = threadIdx.x;
    const int w    = tid >> 6;
    const int lane = tid & 63;

    // XCD-aware swizzle: 8 XCDs, nwg % 8 == 0 (1024 or 512)
    const int cpx = gridDim.x >> 3;
    const int bid = blockIdx.x;
    const int swz = (bid & 7) * cpx + (bid >> 3);

    const int nCol = D_DIM / BN;           // 8 (dual) or 4 (single)
    const int M0 = (swz / nCol) * BM;
    const int N0 = (swz % nCol) * BN;

    // staging: chunk = 16 rows x 32 cols bf16 (1KB); lane -> row=lane>>2, slot=lane&3.
    // LDS written linearly; global src pre-swizzled: stored slot s holds kgrp s^((row>>1)&3).
    const int srow  = lane >> 2;
    const int sslot = lane & 3;
    const int sg    = sslot ^ ((srow >> 1) & 3);

    const u16* pA0 = A + (size_t)(M0 + (w * 2 + 0) * 16 + srow) * KTOT + sg * 8;
    const u16* pA1 = A + (size_t)(M0 + (w * 2 + 1) * 16 + srow) * KTOT + sg * 8;
    const u16* pB0a;
    const u16* pB0b = nullptr;
    const u16* pB1a = nullptr;
    if (DUAL) {
        pB0a = B0g + (size_t)(N0 + w * 16 + srow) * KTOT + sg * 8;
        pB1a = B1g + (size_t)(N0 + w * 16 + srow) * KTOT + sg * 8;
    } else {
        pB0a = B0g + (size_t)(N0 + (w * 2 + 0) * 16 + srow) * KTOT + sg * 8;
        pB0b = B0g + (size_t)(N0 + (w * 2 + 1) * 16 + srow) * KTOT + sg * 8;
    }

    auto stageA = [&](int buf) {
        u16* s = smem + buf * BUF;
        gload16(pA0, s + (w * 2 + 0) * 512); pA0 += 32;
        gload16(pA1, s + (w * 2 + 1) * 512); pA1 += 32;
    };
    auto stageB = [&](int buf) {
        u16* s = smem + buf * BUF;
        if (DUAL) {
            gload16(pB0a, s + 8192 + w * 512);  pB0a += 32;
            gload16(pB1a, s + 12288 + w * 512); pB1a += 32;
        } else {
            gload16(pB0a, s + 8192 + (w * 2 + 0) * 512); pB0a += 32;
            gload16(pB0b, s + 8192 + (w * 2 + 1) * 512); pB0b += 32;
        }
    };

    const int wrow = DUAL ? (w >> 1) * 64 : (w >> 2) * 128;
    const int wcol = DUAL ? (w & 1) * 64 : (w & 3) * 64;
    const int fr = lane & 15;
    const int fq = lane >> 4;

    int offA[MFR], offB[4];
#pragma unroll
    for (int m = 0; m < MFR; ++m) {
        int row = wrow + m * 16 + fr;
        offA[m] = row * 32 + ((fq ^ ((row >> 1) & 3)) << 3);
    }
#pragma unroll
    for (int n = 0; n < 4; ++n) {
        int row = wcol + n * 16 + fr;
        offB[n] = row * 32 + ((fq ^ ((row >> 1) & 3)) << 3);
    }

    f32x4 acc0[MFR][4] = {};
    f32x4 acc1[DUAL ? 4 : 1][4] = {};
    bf16x8 af0[MFR], af1[MFR], b00[4], b01[4];
    bf16x8 b1f[DUAL ? 4 : 1];

    // prologue: 3 tiles in flight, then wait tile 0, barrier, read first frags
    stageA(0); stageB(0); stageA(1); stageB(1); stageA(2); stageB(2);
    asm volatile("s_waitcnt vmcnt(8)" ::: "memory");
    __builtin_amdgcn_s_barrier();
#pragma unroll
    for (int m = 0; m < 4; ++m) af0[m] = *(const bf16x8*)(smem + offA[m]);
#pragma unroll
    for (int n = 0; n < 4; ++n) b00[n] = *(const bf16x8*)(smem + 8192 + offB[n]);

// one K-step: phase A {read rest of buf kt | stageA | BAR | lgkm(4) | MFMA0 | BAR}
//             phase B {read buf kt+1 into NXT | stageB | BAR | lgkm(8) | MFMA1 | BAR}
#define PHASES(KT, AFC, B0C, AFN, B0N)                                               \
  {                                                                                  \
    const int kt_ = (KT);                                                            \
    if (kt_ < NT - 2) { asm volatile("s_waitcnt vmcnt(4)" ::: "memory"); }           \
    else              { asm volatile("s_waitcnt vmcnt(0)" ::: "memory"); }           \
    __builtin_amdgcn_sched_barrier(0);                                               \
    const u16* As_ = smem + (kt_ & 3) * BUF;                                         \
    if constexpr (DUAL) {                                                            \
      _Pragma("unroll") for (int n = 0; n < 4; ++n)                                  \
        b1f[n] = *(const bf16x8*)(As_ + 12288 + offB[n]);                            \
    } else {                                                                         \
      _Pragma("unroll") for (int m = 4; m < MFR; ++m)                                \
        AFC[m] = *(const bf16x8*)(As_ + offA[m]);                                    \
    }                                                                                \
    if (kt_ + 3 < NT) stageA((kt_ + 3) & 3);                                         \
    __builtin_amdgcn_sched_barrier(0);                                               \
    __builtin_amdgcn_s_barrier();                                                    \
    asm volatile("s_waitcnt lgkmcnt(4)" ::: "memory");                               \
    __builtin_amdgcn_sched_barrier(0);                                               \
    __builtin_amdgcn_s_setprio(1);                                                   \
    _Pragma("unroll") for (int m = 0; m < 4; ++m)                                    \
      _Pragma("unroll") for (int n = 0; n < 4; ++n)                                  \
        acc0[m][n] = __builtin_amdgcn_mfma_f32_16x16x32_bf16(AFC[m], B0C[n], acc0[m][n], 0, 0, 0); \
    __builtin_amdgcn_s_setprio(0);                                                   \
    __builtin_amdgcn_sched_barrier(0);                                               \
    __builtin_amdgcn_s_barrier();                                                    \
    const u16* Asn_ = smem + ((kt_ + 1) & 3) * BUF;                                  \
    _Pragma("unroll") for (int m = 0; m < 4; ++m)                                    \
      AFN[m] = *(const bf16x8*)(Asn_ + offA[m]);                                     \
    _Pragma("unroll") for (int n = 0; n < 4; ++n)                                    \
      B0N[n] = *(const bf16x8*)(Asn_ + 8192 + offB[n]);                              \
    if (kt_ + 3 < NT) stageB((kt_ + 3) & 3);                                         \
    __builtin_amdgcn_sched_barrier(0);                                               \
    __builtin_amdgcn_s_barrier();                                                    \
    asm volatile("s_waitcnt lgkmcnt(8)" ::: "memory");                               \
    __builtin_amdgcn_sched_barrier(0);                                               \
    __builtin_amdgcn_s_setprio(1);                                                   \
    if constexpr (DUAL) {                                                            \
      _Pragma("unroll") for (int m = 0; m < 4; ++m)                                  \
        _Pragma("unroll") for (int n = 0; n < 4; ++n)                                \
          acc1[m][n] = __builtin_amdgcn_mfma_f32_16x16x32_bf16(AFC[m], b1f[n], acc1[m][n], 0, 0, 0); \
    } else {                                                                         \
      _Pragma("unroll") for (int m = 4; m < MFR; ++m)                                \
        _Pragma("unroll") for (int n = 0; n < 4; ++n)                                \
          acc0[m][n] = __builtin_amdgcn_mfma_f32_16x16x32_bf16(AFC[m], B0C[n], acc0[m][n], 0, 0, 0); \
    }                                                                                \
    __builtin_amdgcn_s_setprio(0);                                                   \
    __builtin_amdgcn_sched_barrier(0);                                               \
    __builtin_amdgcn_s_barrier();                                                    \
  }

#pragma unroll 1
    for (int kt = 0; kt < NT; kt += 2) {
        PHASES(kt,     af0, b00, af1, b01);
        PHASES(kt + 1, af1, b01, af0, b00);
    }
#undef PHASES

    // epilogue: C/D layout col=lane&15, row=(lane>>4)*4+reg
#pragma unroll
    for (int n = 0; n < 4; ++n) {
        int col = N0 + wcol + n * 16 + fr;
        float b0 = bias0[col];
        float b1 = bias1[col];
#pragma unroll
        for (int m = 0; m < MFR; ++m) {
            int row0 = M0 + wrow + m * 16 + fq * 4;
#pragma unroll
            for (int j = 0; j < 4; ++j) {
                if (DUAL) {
                    float kl = acc0[m][n][j] + b0;
                    float vv = acc1[m][n][j] + b1;
                    float sg2 = 1.0f / (1.0f + __expf(-kl));
                    Uout[(size_t)(row0 + j) * D_DIM + col] = f2bf(sg2 * vv);
                } else {
                    Fout[(size_t)(row0 + j) * D_DIM + col] = (acc0[m][n][j] + b0) / b1;
                }
            }
        }
    }
}

// ---------------- scan pass A: per-chunk carry (x8 vectorized) ----------------
__global__ void chunk_carry_kernel(const u16* __restrict__ u, const float* __restrict__ decay,
                                   float* __restrict__ localc) {
    int id = blockIdx.x * blockDim.x + threadIdx.x;   // B*NCHUNK*(D/8) = 65536
    int d8 = id & 127;
    int c  = (id >> 7) & (NCHUNK - 1);
    int b  = id >> 13;
    float4 dlo = ((const float4*)decay)[d8 * 2];
    float4 dhi = ((const float4*)decay)[d8 * 2 + 1];
    float dec[8] = {dlo.x, dlo.y, dlo.z, dlo.w, dhi.x, dhi.y, dhi.z, dhi.w};
    float carry[8] = {};
    const u16* up = u + ((size_t)b * T_LEN + (size_t)c * CHUNK) * D_DIM + d8 * 8;
    for (int s = 0; s < CHUNK; ++s) {
        u16x8 v = *(const u16x8*)(up + (size_t)s * D_DIM);
#pragma unroll
        for (int j = 0; j < 8; ++j)
            carry[j] = fmaf(carry[j], dec[j], bf2f(v[j]));
    }
    float* lc = localc + ((size_t)(b * NCHUNK + c)) * D_DIM + d8 * 8;
#pragma unroll
    for (int j = 0; j < 8; ++j) lc[j] = carry[j];
}

// ---------------- scan pass B: exclusive scan over chunk carries ----------------
__global__ void carry_scan_kernel(const float* __restrict__ localc, const float* __restrict__ state_p,
                                  const float* __restrict__ decay, float* __restrict__ prefix,
                                  float* __restrict__ final_p) {
    int id = blockIdx.x * blockDim.x + threadIdx.x;   // B*D = 8192
    int d = id & (D_DIM - 1);
    int b = id >> 10;
    float dec = decay[d];
    float dl = dec;
#pragma unroll
    for (int i = 0; i < 6; ++i) dl *= dl;             // dec^64
    float P = state_p[id];
    for (int c = 0; c < NCHUNK; ++c) {
        int idx = (b * NCHUNK + c) * D_DIM + d;
        prefix[idx] = P;
        P = fmaf(P, dl, localc[idx]);
    }
    final_p[id] = P;
}

// ---------------- scan pass C: reconstruct p in place (x8 vectorized) ----------------
__global__ void reconstruct_kernel(u16* __restrict__ u, const float* __restrict__ decay,
                                   const float* __restrict__ prefix) {
    int id = blockIdx.x * blockDim.x + threadIdx.x;   // 65536
    int d8 = id & 127;
    int c  = (id >> 7) & (NCHUNK - 1);
    int b  = id >> 13;
    float4 dlo = ((const float4*)decay)[d8 * 2];
    float4 dhi = ((const float4*)decay)[d8 * 2 + 1];
    float dec[8] = {dlo.x, dlo.y, dlo.z, dlo.w, dhi.x, dhi.y, dhi.z, dhi.w};
    const float* pf = prefix + ((size_t)(b * NCHUNK + c)) * D_DIM + d8 * 8;
    float p[8];
#pragma unroll
    for (int j = 0; j < 8; ++j) p[j] = pf[j];
    u16* up = u + ((size_t)b * T_LEN + (size_t)c * CHUNK) * D_DIM + d8 * 8;
    for (int s = 0; s < CHUNK; ++s) {
        u16x8 v = *(const u16x8*)(up + (size_t)s * D_DIM);
        u16x8 o;
#pragma unroll
        for (int j = 0; j < 8; ++j) {
            p[j] = fmaf(p[j], dec[j], bf2f(v[j]));
            o[j] = f2bf(p[j]);
        }
        *(u16x8*)(up + (size_t)s * D_DIM) = o;
    }
}

extern "C" void kernel_launch(void* const* d_in, const int* in_sizes, int n_in,
                              void* d_out, int out_size, void* d_ws, size_t ws_size,
                              hipStream_t stream) {
    const float* x       = (const float*)d_in[0];
    const float* state_p = (const float*)d_in[1];
    const float* decay   = (const float*)d_in[2];
    const float* mass    = (const float*)d_in[3];
    const float* Wq      = (const float*)d_in[4];
    const float* bq      = (const float*)d_in[5];
    const float* Wk      = (const float*)d_in[6];
    const float* bk      = (const float*)d_in[7];
    const float* Wv      = (const float*)d_in[8];
    const float* bv      = (const float*)d_in[9];

    float* out     = (float*)d_out;
    float* final_p = out + (size_t)M_ROWS * D_DIM;

    // x_bf16 staged in d_out's first 64MB (dead before final GEMM overwrites it)
    u16* xb = (u16*)d_out;

    // workspace layout (~74MB)
    u16* wkb = (u16*)d_ws;
    u16* wvb = wkb + 1048576;
    u16* wqb = wvb + 1048576;
    u16* ub  = wqb + 1048576;                       // u then p in place, 64MB
    float* localc = (float*)(ub + (size_t)M_ROWS * D_DIM);
    float* prefix = localc + B_SZ * NCHUNK * D_DIM;

    convert_kernel<<<4096, 256, 0, stream>>>(x, xb, (M_ROWS * D_DIM) / 4);
    convert3_kernel<<<1024, 256, 0, stream>>>(Wk, Wv, Wq, wkb, wvb, wqb, (D_DIM * D_DIM) / 4);

    // u = sigmoid(x Wk^T + bk) * (x Wv^T + bv)
    gemm4_kernel<true><<<dim3(1024), dim3(512), 0, stream>>>(
        xb, wkb, wvb, bk, bv, ub, nullptr);

    chunk_carry_kernel<<<256, 256, 0, stream>>>(ub, decay, localc);
    carry_scan_kernel<<<32, 256, 0, stream>>>(localc, state_p, decay, prefix, final_p);
    reconstruct_kernel<<<256, 256, 0, stream>>>(ub, decay, prefix);

    // velocities = (p Wq^T + bq) / mass
    gemm4_kernel<false><<<dim3(512), dim3(512), 0, stream>>>(
        ub, wqb, nullptr, bq, mass, nullptr, out);
}

// Round 6
// 309.011 us; speedup vs baseline: 1.0044x; 1.0044x over previous
//
#include <hip/hip_runtime.h>
#include <stdint.h>
#include <stddef.h>

#define D_DIM 1024
#define T_LEN 4096
#define B_SZ 8
#define M_ROWS 32768   // B_SZ * T_LEN
#define KTOT 1024
#define CHUNK 64
#define NCHUNK 64      // T_LEN / CHUNK

typedef unsigned short u16;
typedef unsigned short u16x8 __attribute__((ext_vector_type(8)));
typedef __bf16 bf16x8 __attribute__((ext_vector_type(8)));
typedef float f32x4 __attribute__((ext_vector_type(4)));

__device__ __forceinline__ u16 f2bf(float f) {
    union { float f; unsigned u; } v; v.f = f;
    unsigned r = v.u + 0x7fffu + ((v.u >> 16) & 1u);
    return (u16)(r >> 16);
}
__device__ __forceinline__ float bf2f(u16 h) {
    union { unsigned u; float f; } v; v.u = ((unsigned)h) << 16;
    return v.f;
}

// ---------------- f32 -> bf16 conversion (vectorized) ----------------
__global__ void convert_kernel(const float* __restrict__ src, u16* __restrict__ dst, int n4) {
    int i = blockIdx.x * blockDim.x + threadIdx.x;
    int stride = gridDim.x * blockDim.x;
    for (int j = i; j < n4; j += stride) {
        float4 v = ((const float4*)src)[j];
        ushort4 o;
        o.x = f2bf(v.x); o.y = f2bf(v.y); o.z = f2bf(v.z); o.w = f2bf(v.w);
        ((ushort4*)dst)[j] = o;
    }
}

// Build wcat (Wk/Wv interleaved at 16-row granularity: rows [32g..32g+15]=Wk[16g..],
// rows [32g+16..32g+31]=Wv[16g..]) and wqb (plain bf16 Wq) in one launch.
__global__ void convert_w_kernel(const float* __restrict__ Wk, const float* __restrict__ Wv,
                                 const float* __restrict__ Wq,
                                 u16* __restrict__ wcat, u16* __restrict__ wqb) {
    int total = 3072 * 256;   // 3072 rows x 256 float4
    int stride = gridDim.x * blockDim.x;
    for (int idx = blockIdx.x * blockDim.x + threadIdx.x; idx < total; idx += stride) {
        int r = idx >> 8, c4 = idx & 255;
        const float* src; u16* dst;
        if (r < 2048) {
            int g = r >> 5, j = r & 31;
            src = (j < 16 ? Wk : Wv) + (size_t)(g * 16 + (j & 15)) * D_DIM;
            dst = wcat + (size_t)r * D_DIM;
        } else {
            src = Wq + (size_t)(r - 2048) * D_DIM;
            dst = wqb + (size_t)(r - 2048) * D_DIM;
        }
        float4 v = ((const float4*)src)[c4];
        ushort4 o;
        o.x = f2bf(v.x); o.y = f2bf(v.y); o.z = f2bf(v.z); o.w = f2bf(v.w);
        ((ushort4*)dst)[c4] = o;
    }
}

// ---------------- async global->LDS, 16B per lane ----------------
__device__ __forceinline__ void gload16(const u16* g, u16* l) {
    __builtin_amdgcn_global_load_lds(
        (const __attribute__((address_space(1))) void*)g,
        (__attribute__((address_space(3))) void*)l,
        16, 0, 0);
}

// ---------------- m201-geometry GEMM: C[row,col] = sum_k A[row,k]*B[col,k] ----
// BM=BN=256, BK=64, 8 waves (2Mx4N), per-wave 128x64, LDS 2x64KB dbuf.
// 4 phases per K-tile; phase = {ds-reads for own quadrant | stage 1 half |
// BAR | lgkm(0) | setprio 16 MFMA | BAR}; vmcnt(4) at P1/P3 only.
// K-halves: Kh0 = k 0..31, Kh1 = k 32..63 of the tile; quadrants
// Q0=m0-3/ks0, Q1=m4-7/ks0, Q2=m0-3/ks1, Q3=m4-7/ks1 (16 MFMA each).
// CAT: B = wcat (N=2048), epilogue pairs frag (2p,2p+1) = (k,v) -> u bf16.
// else: B = wq (N=1024), epilogue (acc+bq)/mass -> f32.
template<bool CAT>
__global__ __launch_bounds__(512, 2) void gemm5_kernel(
    const u16* __restrict__ A,
    const u16* __restrict__ Bg,
    const float* __restrict__ bias0,
    const float* __restrict__ bias1,
    u16* __restrict__ Uout,
    float* __restrict__ Fout)
{
    constexpr int NT = KTOT / 64;      // 16 K-tiles
    __shared__ u16 smem[2 * 32768];    // 128 KB: buf*32768 + {A:0 | B:16384} + ks*8192

    const int tid  = threadIdx.x;
    const int w    = tid >> 6;
    const int lane = tid & 63;

    // XCD-aware swizzle (grid % 8 == 0)
    const int cpx = gridDim.x >> 3;
    const int swz = (blockIdx.x & 7) * cpx + (blockIdx.x >> 3);
    const int nCol = CAT ? 8 : 4;
    const int M0 = (swz / nCol) * 256;
    const int N0 = (swz % nCol) * 256;

    // staging: each gload16 covers 16 rows x 32 cols; lane -> row=lane>>2, slot=lane&3;
    // global src pre-swizzled so stored granule s holds k-granule s ^ ((row>>1)&3).
    const int srow = lane >> 2;
    const int sg   = (lane & 3) ^ ((srow >> 1) & 3);

    const u16* pA0 = A  + (size_t)(M0 + w * 32 +      srow) * KTOT + sg * 8;
    const u16* pA1 = A  + (size_t)(M0 + w * 32 + 16 + srow) * KTOT + sg * 8;
    const u16* pB0 = Bg + (size_t)(N0 + w * 32 +      srow) * KTOT + sg * 8;
    const u16* pB1 = Bg + (size_t)(N0 + w * 32 + 16 + srow) * KTOT + sg * 8;

    auto stA = [&](u16* nxt, int h) {
        gload16(pA0, nxt + h * 8192 + w * 1024);       pA0 += 32;
        gload16(pA1, nxt + h * 8192 + w * 1024 + 512); pA1 += 32;
    };
    auto stB = [&](u16* nxt, int h) {
        gload16(pB0, nxt + 16384 + h * 8192 + w * 1024);       pB0 += 32;
        gload16(pB1, nxt + 16384 + h * 8192 + w * 1024 + 512); pB1 += 32;
    };

    const int wrow = (w >> 2) * 128;
    const int wcol = (w & 3) * 64;
    const int fr = lane & 15;
    const int fq = lane >> 4;

    int offA[8], offB[4];
#pragma unroll
    for (int m = 0; m < 8; ++m) {
        int row = wrow + m * 16 + fr;
        offA[m] = row * 32 + ((fq ^ ((row >> 1) & 3)) << 3);
    }
#pragma unroll
    for (int n = 0; n < 4; ++n) {
        int row = wcol + n * 16 + fr;
        offB[n] = 16384 + row * 32 + ((fq ^ ((row >> 1) & 3)) << 3);
    }

    f32x4 acc[8][4] = {};

    // prologue: stage tile 0 (events: A-Kh0, B-Kh0, A-Kh1, B-Kh1), wait first two
    stA(smem, 0); stB(smem, 0); stA(smem, 1); stB(smem, 1);
    asm volatile("s_waitcnt vmcnt(4)" ::: "memory");
    __builtin_amdgcn_s_barrier();

#pragma unroll 1
    for (int t = 0; t < NT; ++t) {
        const u16* cur = smem + (t & 1) * 32768;
        u16* nxt = smem + ((t + 1) & 1) * 32768;
        const bool pf = (t + 1 < NT);

        bf16x8 aA[4], aB[4], bA[4], aC[4], aD[4], bC[4];

        // ---- P0: reads Q0 operands (ks0) ----
#pragma unroll
        for (int n = 0; n < 4; ++n) bA[n] = *(const bf16x8*)(cur + offB[n]);
#pragma unroll
        for (int m = 0; m < 4; ++m) aA[m] = *(const bf16x8*)(cur + offA[m]);
        if (pf) stA(nxt, 0);
        __builtin_amdgcn_s_barrier();
        asm volatile("s_waitcnt lgkmcnt(0)" ::: "memory");
        __builtin_amdgcn_sched_barrier(0);
        __builtin_amdgcn_s_setprio(1);
#pragma unroll
        for (int m = 0; m < 4; ++m)
#pragma unroll
            for (int n = 0; n < 4; ++n)
                acc[m][n] = __builtin_amdgcn_mfma_f32_16x16x32_bf16(aA[m], bA[n], acc[m][n], 0, 0, 0);
        __builtin_amdgcn_s_setprio(0);
        __builtin_amdgcn_sched_barrier(0);
        __builtin_amdgcn_s_barrier();

        // ---- P1: reads A[4-7] ks0 ----
#pragma unroll
        for (int m = 0; m < 4; ++m) aB[m] = *(const bf16x8*)(cur + offA[4 + m]);
        if (pf) stB(nxt, 0);
        __builtin_amdgcn_s_barrier();
        asm volatile("s_waitcnt lgkmcnt(0)" ::: "memory");
        __builtin_amdgcn_sched_barrier(0);
        __builtin_amdgcn_s_setprio(1);
#pragma unroll
        for (int m = 0; m < 4; ++m)
#pragma unroll
            for (int n = 0; n < 4; ++n)
                acc[4 + m][n] = __builtin_amdgcn_mfma_f32_16x16x32_bf16(aB[m], bA[n], acc[4 + m][n], 0, 0, 0);
        __builtin_amdgcn_s_setprio(0);
        __builtin_amdgcn_sched_barrier(0);
        if (pf) { asm volatile("s_waitcnt vmcnt(4)" ::: "memory"); }
        else    { asm volatile("s_waitcnt vmcnt(0)" ::: "memory"); }
        __builtin_amdgcn_s_barrier();

        // ---- P2: reads Q2 operands (ks1) ----
#pragma unroll
        for (int n = 0; n < 4; ++n) bC[n] = *(const bf16x8*)(cur + 8192 + offB[n]);
#pragma unroll
        for (int m = 0; m < 4; ++m) aC[m] = *(const bf16x8*)(cur + 8192 + offA[m]);
        if (pf) stA(nxt, 1);
        __builtin_amdgcn_s_barrier();
        asm volatile("s_waitcnt lgkmcnt(0)" ::: "memory");
        __builtin_amdgcn_sched_barrier(0);
        __builtin_amdgcn_s_setprio(1);
#pragma unroll
        for (int m = 0; m < 4; ++m)
#pragma unroll
            for (int n = 0; n < 4; ++n)
                acc[m][n] = __builtin_amdgcn_mfma_f32_16x16x32_bf16(aC[m], bC[n], acc[m][n], 0, 0, 0);
        __builtin_amdgcn_s_setprio(0);
        __builtin_amdgcn_sched_barrier(0);
        __builtin_amdgcn_s_barrier();

        // ---- P3: reads A[4-7] ks1 ----
#pragma unroll
        for (int m = 0; m < 4; ++m) aD[m] = *(const bf16x8*)(cur + 8192 + offA[4 + m]);
        if (pf) stB(nxt, 1);
        __builtin_amdgcn_s_barrier();
        asm volatile("s_waitcnt lgkmcnt(0)" ::: "memory");
        __builtin_amdgcn_sched_barrier(0);
        __builtin_amdgcn_s_setprio(1);
#pragma unroll
        for (int m = 0; m < 4; ++m)
#pragma unroll
            for (int n = 0; n < 4; ++n)
                acc[4 + m][n] = __builtin_amdgcn_mfma_f32_16x16x32_bf16(aD[m], bC[n], acc[4 + m][n], 0, 0, 0);
        __builtin_amdgcn_s_setprio(0);
        __builtin_amdgcn_sched_barrier(0);
        if (pf) { asm volatile("s_waitcnt vmcnt(4)" ::: "memory"); }
        __builtin_amdgcn_s_barrier();
    }

    // epilogue: C/D layout col=lane&15, row=(lane>>4)*4+reg
    if (CAT) {
        const int ucol0 = N0 / 2 + (w & 3) * 32;
#pragma unroll
        for (int p = 0; p < 2; ++p) {
            int col = ucol0 + p * 16 + fr;
            float b0 = bias0[col];
            float b1 = bias1[col];
#pragma unroll
            for (int m = 0; m < 8; ++m) {
                int row0 = M0 + wrow + m * 16 + fq * 4;
#pragma unroll
                for (int j = 0; j < 4; ++j) {
                    float kl = acc[m][2 * p][j] + b0;
                    float vv = acc[m][2 * p + 1][j] + b1;
                    float sig = 1.0f / (1.0f + __expf(-kl));
                    Uout[(size_t)(row0 + j) * D_DIM + col] = f2bf(sig * vv);
                }
            }
        }
    } else {
#pragma unroll
        for (int n = 0; n < 4; ++n) {
            int col = N0 + wcol + n * 16 + fr;
            float b0 = bias0[col];
            float b1 = bias1[col];
#pragma unroll
            for (int m = 0; m < 8; ++m) {
                int row0 = M0 + wrow + m * 16 + fq * 4;
#pragma unroll
                for (int j = 0; j < 4; ++j)
                    Fout[(size_t)(row0 + j) * D_DIM + col] = (acc[m][n][j] + b0) / b1;
            }
        }
    }
}

// ---------------- scan pass A: per-chunk carry (x8 vectorized) ----------------
__global__ void chunk_carry_kernel(const u16* __restrict__ u, const float* __restrict__ decay,
                                   float* __restrict__ localc) {
    int id = blockIdx.x * blockDim.x + threadIdx.x;   // B*NCHUNK*(D/8) = 65536
    int d8 = id & 127;
    int c  = (id >> 7) & (NCHUNK - 1);
    int b  = id >> 13;
    float4 dlo = ((const float4*)decay)[d8 * 2];
    float4 dhi = ((const float4*)decay)[d8 * 2 + 1];
    float dec[8] = {dlo.x, dlo.y, dlo.z, dlo.w, dhi.x, dhi.y, dhi.z, dhi.w};
    float carry[8] = {};
    const u16* up = u + ((size_t)b * T_LEN + (size_t)c * CHUNK) * D_DIM + d8 * 8;
    for (int s = 0; s < CHUNK; ++s) {
        u16x8 v = *(const u16x8*)(up + (size_t)s * D_DIM);
#pragma unroll
        for (int j = 0; j < 8; ++j)
            carry[j] = fmaf(carry[j], dec[j], bf2f(v[j]));
    }
    float* lc = localc + ((size_t)(b * NCHUNK + c)) * D_DIM + d8 * 8;
#pragma unroll
    for (int j = 0; j < 8; ++j) lc[j] = carry[j];
}

// ---------------- scan pass B: exclusive scan over chunk carries ----------------
__global__ void carry_scan_kernel(const float* __restrict__ localc, const float* __restrict__ state_p,
                                  const float* __restrict__ decay, float* __restrict__ prefix,
                                  float* __restrict__ final_p) {
    int id = blockIdx.x * blockDim.x + threadIdx.x;   // B*D = 8192
    int d = id & (D_DIM - 1);
    int b = id >> 10;
    float dec = decay[d];
    float dl = dec;
#pragma unroll
    for (int i = 0; i < 6; ++i) dl *= dl;             // dec^64
    float P = state_p[id];
    for (int c = 0; c < NCHUNK; ++c) {
        int idx = (b * NCHUNK + c) * D_DIM + d;
        prefix[idx] = P;
        P = fmaf(P, dl, localc[idx]);
    }
    final_p[id] = P;
}

// ---------------- scan pass C: reconstruct p in place (x8 vectorized) ----------------
__global__ void reconstruct_kernel(u16* __restrict__ u, const float* __restrict__ decay,
                                   const float* __restrict__ prefix) {
    int id = blockIdx.x * blockDim.x + threadIdx.x;   // 65536
    int d8 = id & 127;
    int c  = (id >> 7) & (NCHUNK - 1);
    int b  = id >> 13;
    float4 dlo = ((const float4*)decay)[d8 * 2];
    float4 dhi = ((const float4*)decay)[d8 * 2 + 1];
    float dec[8] = {dlo.x, dlo.y, dlo.z, dlo.w, dhi.x, dhi.y, dhi.z, dhi.w};
    const float* pf = prefix + ((size_t)(b * NCHUNK + c)) * D_DIM + d8 * 8;
    float p[8];
#pragma unroll
    for (int j = 0; j < 8; ++j) p[j] = pf[j];
    u16* up = u + ((size_t)b * T_LEN + (size_t)c * CHUNK) * D_DIM + d8 * 8;
    for (int s = 0; s < CHUNK; ++s) {
        u16x8 v = *(const u16x8*)(up + (size_t)s * D_DIM);
        u16x8 o;
#pragma unroll
        for (int j = 0; j < 8; ++j) {
            p[j] = fmaf(p[j], dec[j], bf2f(v[j]));
            o[j] = f2bf(p[j]);
        }
        *(u16x8*)(up + (size_t)s * D_DIM) = o;
    }
}

extern "C" void kernel_launch(void* const* d_in, const int* in_sizes, int n_in,
                              void* d_out, int out_size, void* d_ws, size_t ws_size,
                              hipStream_t stream) {
    const float* x       = (const float*)d_in[0];
    const float* state_p = (const float*)d_in[1];
    const float* decay   = (const float*)d_in[2];
    const float* mass    = (const float*)d_in[3];
    const float* Wq      = (const float*)d_in[4];
    const float* bq      = (const float*)d_in[5];
    const float* Wk      = (const float*)d_in[6];
    const float* bk      = (const float*)d_in[7];
    const float* Wv      = (const float*)d_in[8];
    const float* bv      = (const float*)d_in[9];

    float* out     = (float*)d_out;
    float* final_p = out + (size_t)M_ROWS * D_DIM;

    // x_bf16 staged in d_out's first 64MB (dead before final GEMM overwrites it)
    u16* xb = (u16*)d_out;

    // workspace layout (~74MB)
    u16* wcat = (u16*)d_ws;                          // [2048][1024] interleaved Wk/Wv
    u16* wqb  = wcat + 2048 * 1024;
    u16* ub   = wqb + 1024 * 1024;                   // u then p in place, 64MB
    float* localc = (float*)(ub + (size_t)M_ROWS * D_DIM);
    float* prefix = localc + B_SZ * NCHUNK * D_DIM;

    convert_kernel<<<4096, 256, 0, stream>>>(x, xb, (M_ROWS * D_DIM) / 4);
    convert_w_kernel<<<1536, 256, 0, stream>>>(Wk, Wv, Wq, wcat, wqb);

    // u = sigmoid(x Wk^T + bk) * (x Wv^T + bv)  -- one N=2048 GEMM over wcat
    gemm5_kernel<true><<<dim3(1024), dim3(512), 0, stream>>>(
        xb, wcat, bk, bv, ub, nullptr);

    chunk_carry_kernel<<<256, 256, 0, stream>>>(ub, decay, localc);
    carry_scan_kernel<<<32, 256, 0, stream>>>(localc, state_p, decay, prefix, final_p);
    reconstruct_kernel<<<256, 256, 0, stream>>>(ub, decay, prefix);

    // velocities = (p Wq^T + bq) / mass
    gemm5_kernel<false><<<dim3(512), dim3(512), 0, stream>>>(
        ub, wqb, bq, mass, nullptr, out);
}

// Round 7
// 301.775 us; speedup vs baseline: 1.0285x; 1.0240x over previous
//
#include <hip/hip_runtime.h>
#include <stdint.h>
#include <stddef.h>

#define D_DIM 1024
#define T_LEN 4096
#define B_SZ 8
#define M_ROWS 32768   // B_SZ * T_LEN
#define KTOT 1024
#define CHUNK 64
#define NCHUNK 64      // T_LEN / CHUNK

typedef unsigned short u16;
typedef unsigned short u16x8 __attribute__((ext_vector_type(8)));
typedef __bf16 bf16x8 __attribute__((ext_vector_type(8)));
typedef float f32x4 __attribute__((ext_vector_type(4)));

__device__ __forceinline__ u16 f2bf(float f) {
    union { float f; unsigned u; } v; v.f = f;
    unsigned r = v.u + 0x7fffu + ((v.u >> 16) & 1u);
    return (u16)(r >> 16);
}
__device__ __forceinline__ float bf2f(u16 h) {
    union { unsigned u; float f; } v; v.u = ((unsigned)h) << 16;
    return v.f;
}

// ---------------- f32 -> bf16 conversion (vectorized) ----------------
__global__ void convert_kernel(const float* __restrict__ src, u16* __restrict__ dst, int n4) {
    int i = blockIdx.x * blockDim.x + threadIdx.x;
    int stride = gridDim.x * blockDim.x;
    for (int j = i; j < n4; j += stride) {
        float4 v = ((const float4*)src)[j];
        ushort4 o;
        o.x = f2bf(v.x); o.y = f2bf(v.y); o.z = f2bf(v.z); o.w = f2bf(v.w);
        ((ushort4*)dst)[j] = o;
    }
}

// Build wcat (Wk/Wv interleaved at 16-row granularity) and wqb (bf16 Wq).
__global__ void convert_w_kernel(const float* __restrict__ Wk, const float* __restrict__ Wv,
                                 const float* __restrict__ Wq,
                                 u16* __restrict__ wcat, u16* __restrict__ wqb) {
    int total = 3072 * 256;   // 3072 rows x 256 float4
    int stride = gridDim.x * blockDim.x;
    for (int idx = blockIdx.x * blockDim.x + threadIdx.x; idx < total; idx += stride) {
        int r = idx >> 8, c4 = idx & 255;
        const float* src; u16* dst;
        if (r < 2048) {
            int g = r >> 5, j = r & 31;
            src = (j < 16 ? Wk : Wv) + (size_t)(g * 16 + (j & 15)) * D_DIM;
            dst = wcat + (size_t)r * D_DIM;
        } else {
            src = Wq + (size_t)(r - 2048) * D_DIM;
            dst = wqb + (size_t)(r - 2048) * D_DIM;
        }
        float4 v = ((const float4*)src)[c4];
        ushort4 o;
        o.x = f2bf(v.x); o.y = f2bf(v.y); o.z = f2bf(v.z); o.w = f2bf(v.w);
        ((ushort4*)dst)[c4] = o;
    }
}

// ---------------- async global->LDS, 16B per lane ----------------
__device__ __forceinline__ void gload16(const u16* g, u16* l) {
    __builtin_amdgcn_global_load_lds(
        (const __attribute__((address_space(1))) void*)g,
        (__attribute__((address_space(3))) void*)l,
        16, 0, 0);
}

#define SBAR() __builtin_amdgcn_sched_barrier(0)

// ---------------- read-ahead pipelined GEMM: C[r,c] = sum_k A[r,k]*B[c,k] ----
// BM=BN=256, BK=64, 8 waves (2Mx4N), per-wave 128x64, LDS 2x64KB dbuf.
// 4 phases per K-tile; ds_reads for phase p+1 issued DURING phase p's MFMA
// (compiler emits counted lgkmcnt before each cluster). 2 barriers per K-tile
// (top of p1 / p3) with counted vmcnt(2) covering the half-tile staged 2
// phases earlier. Raw s_barrier (no waitcnt drain).
template<bool CAT>
__global__ __launch_bounds__(512, 2) void gemm6_kernel(
    const u16* __restrict__ A,
    const u16* __restrict__ Bg,
    const float* __restrict__ bias0,
    const float* __restrict__ bias1,
    u16* __restrict__ Uout,
    float* __restrict__ Fout)
{
    constexpr int NT = KTOT / 64;      // 16 K-tiles
    __shared__ u16 smem[2 * 32768];    // 128 KB: buf*32768 + {A:0 | B:16384} + ks*8192

    const int tid  = threadIdx.x;
    const int w    = tid >> 6;
    const int lane = tid & 63;

    // XCD-aware swizzle (grid % 8 == 0)
    const int cpx = gridDim.x >> 3;
    const int swz = (blockIdx.x & 7) * cpx + (blockIdx.x >> 3);
    const int nCol = CAT ? 8 : 4;
    const int M0 = (swz / nCol) * 256;
    const int N0 = (swz % nCol) * 256;

    // staging: each gload16 covers 16 rows x 32 cols; lane -> row=lane>>2, slot=lane&3;
    // global src pre-swizzled so stored granule s holds k-granule s ^ ((row>>1)&3).
    const int srow = lane >> 2;
    const int sg   = (lane & 3) ^ ((srow >> 1) & 3);

    const u16* pA0 = A  + (size_t)(M0 + w * 32 +      srow) * KTOT + sg * 8;
    const u16* pA1 = A  + (size_t)(M0 + w * 32 + 16 + srow) * KTOT + sg * 8;
    const u16* pB0 = Bg + (size_t)(N0 + w * 32 +      srow) * KTOT + sg * 8;
    const u16* pB1 = Bg + (size_t)(N0 + w * 32 + 16 + srow) * KTOT + sg * 8;

    auto stA = [&](u16* nxt, int h) {
        gload16(pA0, nxt + h * 8192 + w * 1024);       pA0 += 32;
        gload16(pA1, nxt + h * 8192 + w * 1024 + 512); pA1 += 32;
    };
    auto stB = [&](u16* nxt, int h) {
        gload16(pB0, nxt + 16384 + h * 8192 + w * 1024);       pB0 += 32;
        gload16(pB1, nxt + 16384 + h * 8192 + w * 1024 + 512); pB1 += 32;
    };

    const int wrow = (w >> 2) * 128;
    const int wcol = (w & 3) * 64;
    const int fr = lane & 15;
    const int fq = lane >> 4;

    int offA[8], offB[4];
#pragma unroll
    for (int m = 0; m < 8; ++m) {
        int row = wrow + m * 16 + fr;
        offA[m] = row * 32 + ((fq ^ ((row >> 1) & 3)) << 3);
    }
#pragma unroll
    for (int n = 0; n < 4; ++n) {
        int row = wcol + n * 16 + fr;
        offB[n] = 16384 + row * 32 + ((fq ^ ((row >> 1) & 3)) << 3);
    }

    f32x4 acc[8][4] = {};
    bf16x8 aA[4], aB[4], aC[4], aD[4], bA[4], bC[4];

    // prologue: stage tile 0, confirm ks0 half, read first fragments
    stA(smem, 0); stB(smem, 0); stA(smem, 1); stB(smem, 1);
    asm volatile("s_waitcnt vmcnt(4)" ::: "memory");
    __builtin_amdgcn_s_barrier();
#pragma unroll
    for (int m = 0; m < 4; ++m) aA[m] = *(const bf16x8*)(smem + offA[m]);
#pragma unroll
    for (int n = 0; n < 4; ++n) bA[n] = *(const bf16x8*)(smem + offB[n]);

#pragma unroll 1
    for (int t = 0; t < NT; ++t) {
        const u16* cur = smem + (t & 1) * 32768;
        u16* nxt = smem + ((t + 1) & 1) * 32768;
        const bool pf = (t + 1 < NT);

        // ---- p0: issue R[p1]=A[4-7]@ks0; stage A-ks0(t+1); MFMA Q0 = aA x bA ----
#pragma unroll
        for (int m = 0; m < 4; ++m) aB[m] = *(const bf16x8*)(cur + offA[4 + m]);
        if (pf) stA(nxt, 0);
        SBAR();
        __builtin_amdgcn_s_setprio(1);
#pragma unroll
        for (int m = 0; m < 4; ++m)
#pragma unroll
            for (int n = 0; n < 4; ++n)
                acc[m][n] = __builtin_amdgcn_mfma_f32_16x16x32_bf16(aA[m], bA[n], acc[m][n], 0, 0, 0);
        __builtin_amdgcn_s_setprio(0);
        SBAR();

        // ---- p1: vmcnt covers SA1,SB1@(t-1) (tile t ks1 data); BAR;
        //          issue R[p2]=A[0-3]@ks1 + B@ks1; stage B-ks0(t+1); MFMA Q1 = aB x bA ----
        if (pf) { asm volatile("s_waitcnt vmcnt(2)" ::: "memory"); }
        else    { asm volatile("s_waitcnt vmcnt(0)" ::: "memory"); }
        __builtin_amdgcn_s_barrier();
#pragma unroll
        for (int m = 0; m < 4; ++m) aC[m] = *(const bf16x8*)(cur + 8192 + offA[m]);
#pragma unroll
        for (int n = 0; n < 4; ++n) bC[n] = *(const bf16x8*)(cur + 8192 + offB[n]);
        if (pf) stB(nxt, 0);
        SBAR();
        __builtin_amdgcn_s_setprio(1);
#pragma unroll
        for (int m = 0; m < 4; ++m)
#pragma unroll
            for (int n = 0; n < 4; ++n)
                acc[4 + m][n] = __builtin_amdgcn_mfma_f32_16x16x32_bf16(aB[m], bA[n], acc[4 + m][n], 0, 0, 0);
        __builtin_amdgcn_s_setprio(0);
        SBAR();

        // ---- p2: issue R[p3]=A[4-7]@ks1; stage A-ks1(t+1); MFMA Q2 = aC x bC ----
#pragma unroll
        for (int m = 0; m < 4; ++m) aD[m] = *(const bf16x8*)(cur + 8192 + offA[4 + m]);
        if (pf) stA(nxt, 1);
        SBAR();
        __builtin_amdgcn_s_setprio(1);
#pragma unroll
        for (int m = 0; m < 4; ++m)
#pragma unroll
            for (int n = 0; n < 4; ++n)
                acc[m][n] = __builtin_amdgcn_mfma_f32_16x16x32_bf16(aC[m], bC[n], acc[m][n], 0, 0, 0);
        __builtin_amdgcn_s_setprio(0);
        SBAR();

        // ---- p3: vmcnt covers SA0,SB0@t (tile t+1 ks0 data); BAR;
        //          issue R[t+1.p0]= next aA,bA; stage B-ks1(t+1); MFMA Q3 = aD x bC ----
        if (pf) { asm volatile("s_waitcnt vmcnt(2)" ::: "memory"); }
        __builtin_amdgcn_s_barrier();
        if (pf) {
#pragma unroll
            for (int m = 0; m < 4; ++m) aA[m] = *(const bf16x8*)(nxt + offA[m]);
#pragma unroll
            for (int n = 0; n < 4; ++n) bA[n] = *(const bf16x8*)(nxt + offB[n]);
            stB(nxt, 1);
        }
        SBAR();
        __builtin_amdgcn_s_setprio(1);
#pragma unroll
        for (int m = 0; m < 4; ++m)
#pragma unroll
            for (int n = 0; n < 4; ++n)
                acc[4 + m][n] = __builtin_amdgcn_mfma_f32_16x16x32_bf16(aD[m], bC[n], acc[4 + m][n], 0, 0, 0);
        __builtin_amdgcn_s_setprio(0);
        SBAR();
    }

    // epilogue: C/D layout col=lane&15, row=(lane>>4)*4+reg
    if (CAT) {
        const int ucol0 = N0 / 2 + (w & 3) * 32;
#pragma unroll
        for (int p = 0; p < 2; ++p) {
            int col = ucol0 + p * 16 + fr;
            float b0 = bias0[col];
            float b1 = bias1[col];
#pragma unroll
            for (int m = 0; m < 8; ++m) {
                int row0 = M0 + wrow + m * 16 + fq * 4;
#pragma unroll
                for (int j = 0; j < 4; ++j) {
                    float kl = acc[m][2 * p][j] + b0;
                    float vv = acc[m][2 * p + 1][j] + b1;
                    float sig = 1.0f / (1.0f + __expf(-kl));
                    Uout[(size_t)(row0 + j) * D_DIM + col] = f2bf(sig * vv);
                }
            }
        }
    } else {
#pragma unroll
        for (int n = 0; n < 4; ++n) {
            int col = N0 + wcol + n * 16 + fr;
            float b0 = bias0[col];
            float b1 = bias1[col];
#pragma unroll
            for (int m = 0; m < 8; ++m) {
                int row0 = M0 + wrow + m * 16 + fq * 4;
#pragma unroll
                for (int j = 0; j < 4; ++j)
                    Fout[(size_t)(row0 + j) * D_DIM + col] = (acc[m][n][j] + b0) / b1;
            }
        }
    }
}

// ---------------- scan pass A: per-chunk carry (x8 vectorized) ----------------
__global__ void chunk_carry_kernel(const u16* __restrict__ u, const float* __restrict__ decay,
                                   float* __restrict__ localc) {
    int id = blockIdx.x * blockDim.x + threadIdx.x;   // B*NCHUNK*(D/8) = 65536
    int d8 = id & 127;
    int c  = (id >> 7) & (NCHUNK - 1);
    int b  = id >> 13;
    float4 dlo = ((const float4*)decay)[d8 * 2];
    float4 dhi = ((const float4*)decay)[d8 * 2 + 1];
    float dec[8] = {dlo.x, dlo.y, dlo.z, dlo.w, dhi.x, dhi.y, dhi.z, dhi.w};
    float carry[8] = {};
    const u16* up = u + ((size_t)b * T_LEN + (size_t)c * CHUNK) * D_DIM + d8 * 8;
    for (int s = 0; s < CHUNK; ++s) {
        u16x8 v = *(const u16x8*)(up + (size_t)s * D_DIM);
#pragma unroll
        for (int j = 0; j < 8; ++j)
            carry[j] = fmaf(carry[j], dec[j], bf2f(v[j]));
    }
    float* lc = localc + ((size_t)(b * NCHUNK + c)) * D_DIM + d8 * 8;
#pragma unroll
    for (int j = 0; j < 8; ++j) lc[j] = carry[j];
}

// ---------------- scan pass B: exclusive scan over chunk carries ----------------
__global__ void carry_scan_kernel(const float* __restrict__ localc, const float* __restrict__ state_p,
                                  const float* __restrict__ decay, float* __restrict__ prefix,
                                  float* __restrict__ final_p) {
    int id = blockIdx.x * blockDim.x + threadIdx.x;   // B*D = 8192
    int d = id & (D_DIM - 1);
    int b = id >> 10;
    float dec = decay[d];
    float dl = dec;
#pragma unroll
    for (int i = 0; i < 6; ++i) dl *= dl;             // dec^64
    float P = state_p[id];
    for (int c = 0; c < NCHUNK; ++c) {
        int idx = (b * NCHUNK + c) * D_DIM + d;
        prefix[idx] = P;
        P = fmaf(P, dl, localc[idx]);
    }
    final_p[id] = P;
}

// ---------------- scan pass C: reconstruct p in place (x8 vectorized) ----------------
__global__ void reconstruct_kernel(u16* __restrict__ u, const float* __restrict__ decay,
                                   const float* __restrict__ prefix) {
    int id = blockIdx.x * blockDim.x + threadIdx.x;   // 65536
    int d8 = id & 127;
    int c  = (id >> 7) & (NCHUNK - 1);
    int b  = id >> 13;
    float4 dlo = ((const float4*)decay)[d8 * 2];
    float4 dhi = ((const float4*)decay)[d8 * 2 + 1];
    float dec[8] = {dlo.x, dlo.y, dlo.z, dlo.w, dhi.x, dhi.y, dhi.z, dhi.w};
    const float* pf = prefix + ((size_t)(b * NCHUNK + c)) * D_DIM + d8 * 8;
    float p[8];
#pragma unroll
    for (int j = 0; j < 8; ++j) p[j] = pf[j];
    u16* up = u + ((size_t)b * T_LEN + (size_t)c * CHUNK) * D_DIM + d8 * 8;
    for (int s = 0; s < CHUNK; ++s) {
        u16x8 v = *(const u16x8*)(up + (size_t)s * D_DIM);
        u16x8 o;
#pragma unroll
        for (int j = 0; j < 8; ++j) {
            p[j] = fmaf(p[j], dec[j], bf2f(v[j]));
            o[j] = f2bf(p[j]);
        }
        *(u16x8*)(up + (size_t)s * D_DIM) = o;
    }
}

extern "C" void kernel_launch(void* const* d_in, const int* in_sizes, int n_in,
                              void* d_out, int out_size, void* d_ws, size_t ws_size,
                              hipStream_t stream) {
    const float* x       = (const float*)d_in[0];
    const float* state_p = (const float*)d_in[1];
    const float* decay   = (const float*)d_in[2];
    const float* mass    = (const float*)d_in[3];
    const float* Wq      = (const float*)d_in[4];
    const float* bq      = (const float*)d_in[5];
    const float* Wk      = (const float*)d_in[6];
    const float* bk      = (const float*)d_in[7];
    const float* Wv      = (const float*)d_in[8];
    const float* bv      = (const float*)d_in[9];

    float* out     = (float*)d_out;
    float* final_p = out + (size_t)M_ROWS * D_DIM;

    // x_bf16 staged in d_out's first 64MB (dead before final GEMM overwrites it)
    u16* xb = (u16*)d_out;

    // workspace layout (~74MB)
    u16* wcat = (u16*)d_ws;                          // [2048][1024] interleaved Wk/Wv
    u16* wqb  = wcat + 2048 * 1024;
    u16* ub   = wqb + 1024 * 1024;                   // u then p in place, 64MB
    float* localc = (float*)(ub + (size_t)M_ROWS * D_DIM);
    float* prefix = localc + B_SZ * NCHUNK * D_DIM;

    convert_kernel<<<4096, 256, 0, stream>>>(x, xb, (M_ROWS * D_DIM) / 4);
    convert_w_kernel<<<1536, 256, 0, stream>>>(Wk, Wv, Wq, wcat, wqb);

    // u = sigmoid(x Wk^T + bk) * (x Wv^T + bv)  -- one N=2048 GEMM over wcat
    gemm6_kernel<true><<<dim3(1024), dim3(512), 0, stream>>>(
        xb, wcat, bk, bv, ub, nullptr);

    chunk_carry_kernel<<<256, 256, 0, stream>>>(ub, decay, localc);
    carry_scan_kernel<<<32, 256, 0, stream>>>(localc, state_p, decay, prefix, final_p);
    reconstruct_kernel<<<256, 256, 0, stream>>>(ub, decay, prefix);

    // velocities = (p Wq^T + bq) / mass
    gemm6_kernel<false><<<dim3(512), dim3(512), 0, stream>>>(
        ub, wqb, bq, mass, nullptr, out);
}

// Round 8
// 300.407 us; speedup vs baseline: 1.0332x; 1.0046x over previous
//
#include <hip/hip_runtime.h>
#include <stdint.h>
#include <stddef.h>

#define D_DIM 1024
#define T_LEN 4096
#define B_SZ 8
#define M_ROWS 32768   // B_SZ * T_LEN
#define KTOT 1024
#define CHUNK 64
#define NCHUNK 64      // T_LEN / CHUNK

typedef unsigned short u16;
typedef unsigned short u16x8 __attribute__((ext_vector_type(8)));
typedef __bf16 bf16x8 __attribute__((ext_vector_type(8)));
typedef float f32x4 __attribute__((ext_vector_type(4)));

__device__ __forceinline__ u16 f2bf(float f) {
    union { float f; unsigned u; } v; v.f = f;
    unsigned r = v.u + 0x7fffu + ((v.u >> 16) & 1u);
    return (u16)(r >> 16);
}
__device__ __forceinline__ float bf2f(u16 h) {
    union { unsigned u; float f; } v; v.u = ((unsigned)h) << 16;
    return v.f;
}

// ---------------- f32 -> bf16 conversion (vectorized) ----------------
__global__ void convert_kernel(const float* __restrict__ src, u16* __restrict__ dst, int n4) {
    int i = blockIdx.x * blockDim.x + threadIdx.x;
    int stride = gridDim.x * blockDim.x;
    for (int j = i; j < n4; j += stride) {
        float4 v = ((const float4*)src)[j];
        ushort4 o;
        o.x = f2bf(v.x); o.y = f2bf(v.y); o.z = f2bf(v.z); o.w = f2bf(v.w);
        ((ushort4*)dst)[j] = o;
    }
}

// Build wcat (Wk/Wv interleaved at 16-row granularity) and wqb (bf16 Wq).
__global__ void convert_w_kernel(const float* __restrict__ Wk, const float* __restrict__ Wv,
                                 const float* __restrict__ Wq,
                                 u16* __restrict__ wcat, u16* __restrict__ wqb) {
    int total = 3072 * 256;   // 3072 rows x 256 float4
    int stride = gridDim.x * blockDim.x;
    for (int idx = blockIdx.x * blockDim.x + threadIdx.x; idx < total; idx += stride) {
        int r = idx >> 8, c4 = idx & 255;
        const float* src; u16* dst;
        if (r < 2048) {
            int g = r >> 5, j = r & 31;
            src = (j < 16 ? Wk : Wv) + (size_t)(g * 16 + (j & 15)) * D_DIM;
            dst = wcat + (size_t)r * D_DIM;
        } else {
            src = Wq + (size_t)(r - 2048) * D_DIM;
            dst = wqb + (size_t)(r - 2048) * D_DIM;
        }
        float4 v = ((const float4*)src)[c4];
        ushort4 o;
        o.x = f2bf(v.x); o.y = f2bf(v.y); o.z = f2bf(v.z); o.w = f2bf(v.w);
        ((ushort4*)dst)[c4] = o;
    }
}

// ---------------- async global->LDS, 16B per lane ----------------
__device__ __forceinline__ void gload16(const u16* g, u16* l) {
    __builtin_amdgcn_global_load_lds(
        (const __attribute__((address_space(1))) void*)g,
        (__attribute__((address_space(3))) void*)l,
        16, 0, 0);
}

// phase-top wait: drain previous phase's ds_reads, then fence so MFMA can't
// hoist above (rule #18); body below is left UNFENCED so the scheduler
// interleaves this phase's ds_reads/stages into the MFMA stream.
#define LGKM0_FENCE() do { \
    asm volatile("s_waitcnt lgkmcnt(0)" ::: "memory"); \
    __builtin_amdgcn_sched_barrier(0); } while (0)

// ---------------- free-scheduled pipelined GEMM: C[r,c] = sum_k A[r,k]*B[c,k]
// BM=BN=256, BK=64, 8 waves (2Mx4N), per-wave 128x64, LDS 2x64KB dbuf.
// 4 phases/K-tile; phase = {[vmcnt/BAR] lgkm0-fence | reads(p+1) + stage +
// 16 MFMA free-scheduled}. At each phase top only the previous phase's
// reads are outstanding -> lgkmcnt(0) == exact counted wait. 2 barriers/tile.
template<bool CAT>
__global__ __launch_bounds__(512, 2) void gemm7_kernel(
    const u16* __restrict__ A,
    const u16* __restrict__ Bg,
    const float* __restrict__ bias0,
    const float* __restrict__ bias1,
    u16* __restrict__ Uout,
    float* __restrict__ Fout)
{
    constexpr int NT = KTOT / 64;      // 16 K-tiles
    __shared__ u16 smem[2 * 32768];    // 128 KB: buf*32768 + {A:0 | B:16384} + ks*8192

    const int tid  = threadIdx.x;
    const int w    = tid >> 6;
    const int lane = tid & 63;

    // XCD-aware swizzle (grid % 8 == 0)
    const int cpx = gridDim.x >> 3;
    const int swz = (blockIdx.x & 7) * cpx + (blockIdx.x >> 3);
    const int nCol = CAT ? 8 : 4;
    const int M0 = (swz / nCol) * 256;
    const int N0 = (swz % nCol) * 256;

    // staging: each gload16 covers 16 rows x 32 cols; lane -> row=lane>>2, slot=lane&3;
    // global src pre-swizzled so stored granule s holds k-granule s ^ ((row>>1)&3).
    const int srow = lane >> 2;
    const int sg   = (lane & 3) ^ ((srow >> 1) & 3);

    const u16* pA0 = A  + (size_t)(M0 + w * 32 +      srow) * KTOT + sg * 8;
    const u16* pA1 = A  + (size_t)(M0 + w * 32 + 16 + srow) * KTOT + sg * 8;
    const u16* pB0 = Bg + (size_t)(N0 + w * 32 +      srow) * KTOT + sg * 8;
    const u16* pB1 = Bg + (size_t)(N0 + w * 32 + 16 + srow) * KTOT + sg * 8;

    auto stA = [&](u16* nxt, int h) {
        gload16(pA0, nxt + h * 8192 + w * 1024);       pA0 += 32;
        gload16(pA1, nxt + h * 8192 + w * 1024 + 512); pA1 += 32;
    };
    auto stB = [&](u16* nxt, int h) {
        gload16(pB0, nxt + 16384 + h * 8192 + w * 1024);       pB0 += 32;
        gload16(pB1, nxt + 16384 + h * 8192 + w * 1024 + 512); pB1 += 32;
    };

    const int wrow = (w >> 2) * 128;
    const int wcol = (w & 3) * 64;
    const int fr = lane & 15;
    const int fq = lane >> 4;

    int offA[8], offB[4];
#pragma unroll
    for (int m = 0; m < 8; ++m) {
        int row = wrow + m * 16 + fr;
        offA[m] = row * 32 + ((fq ^ ((row >> 1) & 3)) << 3);
    }
#pragma unroll
    for (int n = 0; n < 4; ++n) {
        int row = wcol + n * 16 + fr;
        offB[n] = 16384 + row * 32 + ((fq ^ ((row >> 1) & 3)) << 3);
    }

    f32x4 acc[8][4] = {};
    bf16x8 aA[4], aB[4], aC[4], aD[4], bA[4], bC[4];

    // prologue: stage tile 0, confirm ks0 half, read first fragments
    stA(smem, 0); stB(smem, 0); stA(smem, 1); stB(smem, 1);
    asm volatile("s_waitcnt vmcnt(4)" ::: "memory");
    __builtin_amdgcn_s_barrier();
#pragma unroll
    for (int m = 0; m < 4; ++m) aA[m] = *(const bf16x8*)(smem + offA[m]);
#pragma unroll
    for (int n = 0; n < 4; ++n) bA[n] = *(const bf16x8*)(smem + offB[n]);

#pragma unroll 1
    for (int t = 0; t < NT; ++t) {
        const u16* cur = smem + (t & 1) * 32768;
        u16* nxt = smem + ((t + 1) & 1) * 32768;
        const bool pf = (t + 1 < NT);

        // ===== p0: wait {aA,bA}; body: read aB + stage A-ks0(t+1) + MFMA Q0 =====
        LGKM0_FENCE();
#pragma unroll
        for (int m = 0; m < 4; ++m) aB[m] = *(const bf16x8*)(cur + offA[4 + m]);
        if (pf) stA(nxt, 0);
#pragma unroll
        for (int m = 0; m < 4; ++m)
#pragma unroll
            for (int n = 0; n < 4; ++n)
                acc[m][n] = __builtin_amdgcn_mfma_f32_16x16x32_bf16(aA[m], bA[n], acc[m][n], 0, 0, 0);

        // ===== p1: vmcnt covers tile-t ks1 data; BAR; wait {aB};
        //           body: read aC,bC + stage B-ks0(t+1) + MFMA Q1 =====
        if (pf) { asm volatile("s_waitcnt vmcnt(2)" ::: "memory"); }
        else    { asm volatile("s_waitcnt vmcnt(0)" ::: "memory"); }
        __builtin_amdgcn_s_barrier();
        LGKM0_FENCE();
#pragma unroll
        for (int m = 0; m < 4; ++m) aC[m] = *(const bf16x8*)(cur + 8192 + offA[m]);
#pragma unroll
        for (int n = 0; n < 4; ++n) bC[n] = *(const bf16x8*)(cur + 8192 + offB[n]);
        if (pf) stB(nxt, 0);
#pragma unroll
        for (int m = 0; m < 4; ++m)
#pragma unroll
            for (int n = 0; n < 4; ++n)
                acc[4 + m][n] = __builtin_amdgcn_mfma_f32_16x16x32_bf16(aB[m], bA[n], acc[4 + m][n], 0, 0, 0);

        // ===== p2: wait {aC,bC}; body: read aD + stage A-ks1(t+1) + MFMA Q2 =====
        LGKM0_FENCE();
#pragma unroll
        for (int m = 0; m < 4; ++m) aD[m] = *(const bf16x8*)(cur + 8192 + offA[4 + m]);
        if (pf) stA(nxt, 1);
#pragma unroll
        for (int m = 0; m < 4; ++m)
#pragma unroll
            for (int n = 0; n < 4; ++n)
                acc[m][n] = __builtin_amdgcn_mfma_f32_16x16x32_bf16(aC[m], bC[n], acc[m][n], 0, 0, 0);

        // ===== p3: vmcnt covers tile-(t+1) ks0 data; BAR; wait {aD};
        //           body: read next aA,bA + stage B-ks1(t+1) + MFMA Q3 =====
        if (pf) { asm volatile("s_waitcnt vmcnt(2)" ::: "memory"); }
        __builtin_amdgcn_s_barrier();
        LGKM0_FENCE();
        if (pf) {
#pragma unroll
            for (int m = 0; m < 4; ++m) aA[m] = *(const bf16x8*)(nxt + offA[m]);
#pragma unroll
            for (int n = 0; n < 4; ++n) bA[n] = *(const bf16x8*)(nxt + offB[n]);
            stB(nxt, 1);
        }
#pragma unroll
        for (int m = 0; m < 4; ++m)
#pragma unroll
            for (int n = 0; n < 4; ++n)
                acc[4 + m][n] = __builtin_amdgcn_mfma_f32_16x16x32_bf16(aD[m], bC[n], acc[4 + m][n], 0, 0, 0);
    }

    // final drain before epilogue (last reads consumed; nothing outstanding matters)
    asm volatile("s_waitcnt lgkmcnt(0) vmcnt(0)" ::: "memory");

    // epilogue: C/D layout col=lane&15, row=(lane>>4)*4+reg
    if (CAT) {
        const int ucol0 = N0 / 2 + (w & 3) * 32;
#pragma unroll
        for (int p = 0; p < 2; ++p) {
            int col = ucol0 + p * 16 + fr;
            float b0 = bias0[col];
            float b1 = bias1[col];
#pragma unroll
            for (int m = 0; m < 8; ++m) {
                int row0 = M0 + wrow + m * 16 + fq * 4;
#pragma unroll
                for (int j = 0; j < 4; ++j) {
                    float kl = acc[m][2 * p][j] + b0;
                    float vv = acc[m][2 * p + 1][j] + b1;
                    float sig = 1.0f / (1.0f + __expf(-kl));
                    Uout[(size_t)(row0 + j) * D_DIM + col] = f2bf(sig * vv);
                }
            }
        }
    } else {
#pragma unroll
        for (int n = 0; n < 4; ++n) {
            int col = N0 + wcol + n * 16 + fr;
            float b0 = bias0[col];
            float b1 = bias1[col];
#pragma unroll
            for (int m = 0; m < 8; ++m) {
                int row0 = M0 + wrow + m * 16 + fq * 4;
#pragma unroll
                for (int j = 0; j < 4; ++j)
                    Fout[(size_t)(row0 + j) * D_DIM + col] = (acc[m][n][j] + b0) / b1;
            }
        }
    }
}

// ---------------- scan pass A: per-chunk carry (x8 vectorized) ----------------
__global__ void chunk_carry_kernel(const u16* __restrict__ u, const float* __restrict__ decay,
                                   float* __restrict__ localc) {
    int id = blockIdx.x * blockDim.x + threadIdx.x;   // B*NCHUNK*(D/8) = 65536
    int d8 = id & 127;
    int c  = (id >> 7) & (NCHUNK - 1);
    int b  = id >> 13;
    float4 dlo = ((const float4*)decay)[d8 * 2];
    float4 dhi = ((const float4*)decay)[d8 * 2 + 1];
    float dec[8] = {dlo.x, dlo.y, dlo.z, dlo.w, dhi.x, dhi.y, dhi.z, dhi.w};
    float carry[8] = {};
    const u16* up = u + ((size_t)b * T_LEN + (size_t)c * CHUNK) * D_DIM + d8 * 8;
    for (int s = 0; s < CHUNK; ++s) {
        u16x8 v = *(const u16x8*)(up + (size_t)s * D_DIM);
#pragma unroll
        for (int j = 0; j < 8; ++j)
            carry[j] = fmaf(carry[j], dec[j], bf2f(v[j]));
    }
    float* lc = localc + ((size_t)(b * NCHUNK + c)) * D_DIM + d8 * 8;
#pragma unroll
    for (int j = 0; j < 8; ++j) lc[j] = carry[j];
}

// ---------------- scan pass B: exclusive scan over chunk carries ----------------
__global__ void carry_scan_kernel(const float* __restrict__ localc, const float* __restrict__ state_p,
                                  const float* __restrict__ decay, float* __restrict__ prefix,
                                  float* __restrict__ final_p) {
    int id = blockIdx.x * blockDim.x + threadIdx.x;   // B*D = 8192
    int d = id & (D_DIM - 1);
    int b = id >> 10;
    float dec = decay[d];
    float dl = dec;
#pragma unroll
    for (int i = 0; i < 6; ++i) dl *= dl;             // dec^64
    float P = state_p[id];
    for (int c = 0; c < NCHUNK; ++c) {
        int idx = (b * NCHUNK + c) * D_DIM + d;
        prefix[idx] = P;
        P = fmaf(P, dl, localc[idx]);
    }
    final_p[id] = P;
}

// ---------------- scan pass C: reconstruct p in place (x8 vectorized) ----------------
__global__ void reconstruct_kernel(u16* __restrict__ u, const float* __restrict__ decay,
                                   const float* __restrict__ prefix) {
    int id = blockIdx.x * blockDim.x + threadIdx.x;   // 65536
    int d8 = id & 127;
    int c  = (id >> 7) & (NCHUNK - 1);
    int b  = id >> 13;
    float4 dlo = ((const float4*)decay)[d8 * 2];
    float4 dhi = ((const float4*)decay)[d8 * 2 + 1];
    float dec[8] = {dlo.x, dlo.y, dlo.z, dlo.w, dhi.x, dhi.y, dhi.z, dhi.w};
    const float* pf = prefix + ((size_t)(b * NCHUNK + c)) * D_DIM + d8 * 8;
    float p[8];
#pragma unroll
    for (int j = 0; j < 8; ++j) p[j] = pf[j];
    u16* up = u + ((size_t)b * T_LEN + (size_t)c * CHUNK) * D_DIM + d8 * 8;
    for (int s = 0; s < CHUNK; ++s) {
        u16x8 v = *(const u16x8*)(up + (size_t)s * D_DIM);
        u16x8 o;
#pragma unroll
        for (int j = 0; j < 8; ++j) {
            p[j] = fmaf(p[j], dec[j], bf2f(v[j]));
            o[j] = f2bf(p[j]);
        }
        *(u16x8*)(up + (size_t)s * D_DIM) = o;
    }
}

extern "C" void kernel_launch(void* const* d_in, const int* in_sizes, int n_in,
                              void* d_out, int out_size, void* d_ws, size_t ws_size,
                              hipStream_t stream) {
    const float* x       = (const float*)d_in[0];
    const float* state_p = (const float*)d_in[1];
    const float* decay   = (const float*)d_in[2];
    const float* mass    = (const float*)d_in[3];
    const float* Wq      = (const float*)d_in[4];
    const float* bq      = (const float*)d_in[5];
    const float* Wk      = (const float*)d_in[6];
    const float* bk      = (const float*)d_in[7];
    const float* Wv      = (const float*)d_in[8];
    const float* bv      = (const float*)d_in[9];

    float* out     = (float*)d_out;
    float* final_p = out + (size_t)M_ROWS * D_DIM;

    // x_bf16 staged in d_out's first 64MB (dead before final GEMM overwrites it)
    u16* xb = (u16*)d_out;

    // workspace layout (~74MB)
    u16* wcat = (u16*)d_ws;                          // [2048][1024] interleaved Wk/Wv
    u16* wqb  = wcat + 2048 * 1024;
    u16* ub   = wqb + 1024 * 1024;                   // u then p in place, 64MB
    float* localc = (float*)(ub + (size_t)M_ROWS * D_DIM);
    float* prefix = localc + B_SZ * NCHUNK * D_DIM;

    convert_kernel<<<4096, 256, 0, stream>>>(x, xb, (M_ROWS * D_DIM) / 4);
    convert_w_kernel<<<1536, 256, 0, stream>>>(Wk, Wv, Wq, wcat, wqb);

    // u = sigmoid(x Wk^T + bk) * (x Wv^T + bv)  -- one N=2048 GEMM over wcat
    gemm7_kernel<true><<<dim3(1024), dim3(512), 0, stream>>>(
        xb, wcat, bk, bv, ub, nullptr);

    chunk_carry_kernel<<<256, 256, 0, stream>>>(ub, decay, localc);
    carry_scan_kernel<<<32, 256, 0, stream>>>(localc, state_p, decay, prefix, final_p);
    reconstruct_kernel<<<256, 256, 0, stream>>>(ub, decay, prefix);

    // velocities = (p Wq^T + bq) / mass
    gemm7_kernel<false><<<dim3(512), dim3(512), 0, stream>>>(
        ub, wqb, bq, mass, nullptr, out);
}